// Round 8
// baseline (315.304 us; speedup 1.0000x reference)
//
#include <hip/hip_runtime.h>
#include <cstdint>
#include <cstddef>

#define HID 128
#define SEQL 28
#define INP 28
#define NL 10
#define NC 10
#define BATCH 4096
#define BB 16             // batch rows per block
#define STRD 136          // padded row stride in halfs (272 B, b128-aligned)
#define BUFH (16 * STRD)  // halfs per 16x128 activation panel

typedef _Float16 half8 __attribute__((ext_vector_type(8)));
typedef _Float16 half4 __attribute__((ext_vector_type(4)));
typedef float    f32x4 __attribute__((ext_vector_type(4)));

// ws: seq [BATCH][SEQL][HID] f16 @ 0 (group-boundary activations; same-block RW only)

__device__ __forceinline__ float tanh_fast(float v) {
  float e = __expf(2.f * v);
  return 1.f - 2.f / (e + 1.f);
}

// 512 threads = 8 waves. Layer groups {0-3},{4-7},{8-9}.
// G0/G1: wave = (l = wid&3, ch = wid>>2) owns layer l, n-cols [64ch,64ch+64), K=256.
// G2   : waves 0-3 active: (l = wid&1, ch = (wid>>1)&1); wid 4-7 idle.
// NO __syncthreads in the tick loop: per-wave LDS progress counters.
// prog[w] = tau+1 is posted after wave w finishes tick tau, so "neighbor done
// with tick tau-1" == prog >= tau. (Round 7 raced by waiting tau-1.)
// Each wave waits on {partner, layer l-1 pair, layer l+1 pair}, computes cell
// (l, t=tau-l), posts after s_waitcnt lgkmcnt(0) ONLY (global seq traffic
// drains at the group-boundary __syncthreads, not per tick).
// LDS slots: X(p)=slot p; O(l,p)=slot 2+2l+p. MFMA: A=weights, B=acts (D: col=m).
__global__ __launch_bounds__(512, 2) void rnn_fused(
    const float* __restrict__ x,
    const float* __restrict__ Wih0,
    const float* __restrict__ Wih,
    const float* __restrict__ Whh,
    const float* __restrict__ bih,
    const float* __restrict__ bhh,
    const float* __restrict__ fcW,
    const float* __restrict__ fcb,
    _Float16* __restrict__ seq,
    float* __restrict__ out) {
  __shared__ _Float16 lds[BUFH * 10] __attribute__((aligned(16)));
  __shared__ int prog[8];

  const int tid    = threadIdx.x;
  const int lane15 = tid & 15;
  const int quad   = (tid >> 4) & 3;
  const int wid    = tid >> 6;
  const int lane   = tid & 63;
  const int b0     = blockIdx.x * BB;
  const int frow   = lane >> 2;      // fill: 16 rows
  const int fq     = lane & 3;       // fill: 4 col-segments

  half8 bfrag[4][8];
  float biasv[4][4];

  for (int g = 0; g < 3; ++g) {
    const int  NLg    = (g < 2) ? 4 : 2;
    const bool active = (g < 2) || (wid < 4);
    const int  l      = (g < 2) ? (wid & 3) : (wid & 1);
    const int  ch     = (g < 2) ? (wid >> 2) : ((wid >> 1) & 1);
    const int  gl     = g * 4 + l;
    const int  tb     = ch * 4;
    const int  TICKS  = SEQL + NLg - 1;
    const bool fillw  = active && (l == 0);
    const bool loader = fillw && (g > 0 || ch == 0);
    const bool wr_seq = (g < 2) && (l == NLg - 1);

    int wl[5]; int nw = 0;
    if (active) {
      const int stride = (g < 2) ? 4 : 2;
      wl[nw++] = (g < 2) ? (wid ^ 4) : (wid ^ 2);          // partner (h half)
      if (l > 0)       { wl[nw++] = l - 1; wl[nw++] = l - 1 + stride; }  // producers
      if (l < NLg - 1) { wl[nw++] = l + 1; wl[nw++] = l + 1 + stride; }  // consumers
    }

    // ---- stage this wave's weights as f16 A-frags (f32 source, L2-hot) ----
    if (active) {
      const float* WihS = (gl == 0) ? Wih0 : Wih + (size_t)(gl - 1) * HID * HID;
      const float* WhhS = Whh + (size_t)gl * HID * HID;
#pragma unroll
      for (int nt = 0; nt < 4; ++nt) {
        const int n = (tb + nt) * 16 + lane15;
#pragma unroll
        for (int ks = 0; ks < 8; ++ks) {
          half8 h;
          if (gl == 0 && ks < 4) {       // layer 0: x zero-padded to 32 cols
            if (ks == 0) {
#pragma unroll
              for (int j = 0; j < 8; ++j) {
                int c = quad * 8 + j;
                h[j] = (_Float16)((c < INP) ? Wih0[n * INP + c] : 0.f);
              }
            } else {
#pragma unroll
              for (int j = 0; j < 8; ++j) h[j] = (_Float16)0.f;  // never used
            }
          } else {
            const float* p = (ks < 4) ? (WihS + (size_t)n * HID + ks * 32 + quad * 8)
                                      : (WhhS + (size_t)n * HID + (ks - 4) * 32 + quad * 8);
            float4 f0 = *(const float4*)p;
            float4 f1 = *(const float4*)(p + 4);
            h[0] = (_Float16)f0.x; h[1] = (_Float16)f0.y;
            h[2] = (_Float16)f0.z; h[3] = (_Float16)f0.w;
            h[4] = (_Float16)f1.x; h[5] = (_Float16)f1.y;
            h[6] = (_Float16)f1.z; h[7] = (_Float16)f1.w;
          }
          bfrag[nt][ks] = h;
        }
#pragma unroll
        for (int r = 0; r < 4; ++r) {
          int nn = (tb + nt) * 16 + quad * 4 + r;
          biasv[nt][r] = bih[gl * HID + nn] + bhh[gl * HID + nn];
        }
      }
    }
    __syncthreads();  // prev group's LDS reads done + its seq stores drained

    {  // zero all O slots (h=0 at t=0)
      uint4 z; z.x = z.y = z.z = z.w = 0u;
      for (int i = tid; i < (BUFH * 8) / 8; i += 512)
        ((uint4*)(lds + 2 * BUFH))[i] = z;
    }
    if (tid < 8) prog[tid] = 0;

    // ---- prefill X(0) with t=0; issue t=1 into regs (2-tick pipeline) ----
    float4 xA0, xA1, xB0, xB1;
    uint4  sA0, sA1, sB0, sB1;
    if (g == 0) {
      if (loader) {
        const float* xb = x + ((size_t)(b0 + frow) * SEQL + 0) * INP + fq * 8;
        xA0 = *(const float4*)xb;
        xA1 = (fq < 3) ? *(const float4*)(xb + 4) : (float4){0.f, 0.f, 0.f, 0.f};
        half8 h;
        h[0] = (_Float16)xA0.x; h[1] = (_Float16)xA0.y;
        h[2] = (_Float16)xA0.z; h[3] = (_Float16)xA0.w;
        h[4] = (_Float16)xA1.x; h[5] = (_Float16)xA1.y;
        h[6] = (_Float16)xA1.z; h[7] = (_Float16)xA1.w;
        *(half8*)(lds + frow * STRD + fq * 8) = h;
        const float* xb1 = x + ((size_t)(b0 + frow) * SEQL + 1) * INP + fq * 8;
        xA0 = *(const float4*)xb1;
        xA1 = (fq < 3) ? *(const float4*)(xb1 + 4) : (float4){0.f, 0.f, 0.f, 0.f};
      }
    } else {
      if (loader) {
        const int c0 = ch * 64 + fq * 16;
        const _Float16* sp = seq + ((size_t)(b0 + frow) * SEQL + 0) * HID + c0;
        sA0 = *(const uint4*)sp; sA1 = *(const uint4*)(sp + 8);
        *(uint4*)(lds + frow * STRD + c0)     = sA0;
        *(uint4*)(lds + frow * STRD + c0 + 8) = sA1;
        const _Float16* sp1 = seq + ((size_t)(b0 + frow) * SEQL + 1) * HID + c0;
        sA0 = *(const uint4*)sp1; sA1 = *(const uint4*)(sp1 + 8);
      }
    }
    __syncthreads();

    // ---------------- tick loop (no block barriers inside) ----------------
    for (int tau = 0; tau < TICKS; ++tau) {
      const int pt = tau & 1;
      const int t  = tau - l;
      // 1. issue global load for input(t = tau+2)
      if (loader && (tau + 2) < SEQL) {
        if (g == 0) {
          const float* xb = x + ((size_t)(b0 + frow) * SEQL + (tau + 2)) * INP + fq * 8;
          xB0 = *(const float4*)xb;
          xB1 = (fq < 3) ? *(const float4*)(xb + 4) : (float4){0.f, 0.f, 0.f, 0.f};
        } else {
          const int c0 = ch * 64 + fq * 16;
          const _Float16* sp = seq + ((size_t)(b0 + frow) * SEQL + (tau + 2)) * HID + c0;
          sB0 = *(const uint4*)sp; sB1 = *(const uint4*)(sp + 8);
        }
      }
      // 2. wait for neighbors to FINISH tick tau-1 (prog >= tau) -- r7 fix
      if (active) {
        for (int i = 0; i < nw; ++i) {
          volatile int* p = prog + wl[i];
          while (*p < tau) __builtin_amdgcn_s_sleep(1);
        }
      }
      // 3. compute cell (l, t)
      const bool act = active && (t >= 0) && (t < SEQL);
      if (act) {
        const _Float16* INb = (l == 0) ? lds + pt * BUFH
                                       : lds + (2 + 2 * (l - 1) + (1 - pt)) * BUFH;
        const _Float16* Hb  = lds + (2 + 2 * l + (1 - pt)) * BUFH;
        _Float16*       Ob  = lds + (2 + 2 * l + pt) * BUFH;
        half8 af[8];
        if (gl != 0) {
#pragma unroll
          for (int ks = 0; ks < 4; ++ks)
            af[ks] = *(const half8*)(INb + lane15 * STRD + ks * 32 + quad * 8);
        } else {
          af[0] = *(const half8*)(INb + lane15 * STRD + quad * 8);
        }
#pragma unroll
        for (int ks = 0; ks < 4; ++ks)
          af[4 + ks] = *(const half8*)(Hb + lane15 * STRD + ks * 32 + quad * 8);
        f32x4 acc[4];
#pragma unroll
        for (int nt = 0; nt < 4; ++nt)
          acc[nt] = (f32x4){biasv[nt][0], biasv[nt][1], biasv[nt][2], biasv[nt][3]};
        if (gl != 0) {
#pragma unroll
          for (int ks = 0; ks < 4; ++ks)
#pragma unroll
            for (int nt = 0; nt < 4; ++nt)
              acc[nt] = __builtin_amdgcn_mfma_f32_16x16x32_f16(bfrag[nt][ks], af[ks], acc[nt], 0, 0, 0);
        } else {
#pragma unroll
          for (int nt = 0; nt < 4; ++nt)
            acc[nt] = __builtin_amdgcn_mfma_f32_16x16x32_f16(bfrag[nt][0], af[0], acc[nt], 0, 0, 0);
        }
#pragma unroll
        for (int ks = 0; ks < 4; ++ks)
#pragma unroll
          for (int nt = 0; nt < 4; ++nt)
            acc[nt] = __builtin_amdgcn_mfma_f32_16x16x32_f16(bfrag[nt][4 + ks], af[4 + ks], acc[nt], 0, 0, 0);
#pragma unroll
        for (int nt = 0; nt < 4; ++nt) {
          half4 h4;
#pragma unroll
          for (int r = 0; r < 4; ++r) h4[r] = (_Float16)tanh_fast(acc[nt][r]);
          const int n4 = (tb + nt) * 16 + quad * 4;
          *(half4*)(Ob + lane15 * STRD + n4) = h4;
          if (wr_seq)   // consumed next group (after a real __syncthreads)
            *(half4*)(seq + ((size_t)(b0 + lane15) * SEQL + t) * HID + n4) = h4;
        }
      }
      // 4. store input(t = tau+1) into X(1-pt) -- before flag post
      if (loader && (tau + 1) < SEQL) {
        if (g == 0) {
          half8 h;
          h[0] = (_Float16)xA0.x; h[1] = (_Float16)xA0.y;
          h[2] = (_Float16)xA0.z; h[3] = (_Float16)xA0.w;
          h[4] = (_Float16)xA1.x; h[5] = (_Float16)xA1.y;
          h[6] = (_Float16)xA1.z; h[7] = (_Float16)xA1.w;
          *(half8*)(lds + (1 - pt) * BUFH + frow * STRD + fq * 8) = h;
          xA0 = xB0; xA1 = xB1;
        } else {
          const int c0 = ch * 64 + fq * 16;
          *(uint4*)(lds + (1 - pt) * BUFH + frow * STRD + c0)     = sA0;
          *(uint4*)(lds + (1 - pt) * BUFH + frow * STRD + c0 + 8) = sA1;
          sA0 = sB0; sA1 = sB1;
        }
      }
      // 5. post progress: LDS writes drained; global queue stays in flight
      if (active) {
        __asm__ __volatile__("s_waitcnt lgkmcnt(0)" ::: "memory");
        if (lane == 0) *(volatile int*)(prog + wid) = tau + 1;
      }
    }
  }
  __syncthreads();

  // --- FC on layer-9 h at t=27: G2 local l=1, tau=28 (pt=0) -> slot 4 ---
  if (tid < BB * NC) {
    int c = tid >> 4;
    int b = tid & 15;
    float a = fcb[c];
    const float* wr = fcW + c * HID;
    const _Float16* hr = lds + 4 * BUFH + b * STRD;
#pragma unroll 4
    for (int k = 0; k < HID; ++k) a += (float)hr[k] * wr[k];
    out[(size_t)(b0 + b) * NC + c] = a;
  }
}

extern "C" void kernel_launch(void* const* d_in, const int* in_sizes, int n_in,
                              void* d_out, int out_size, void* d_ws, size_t ws_size,
                              hipStream_t stream) {
  const float* x    = (const float*)d_in[0];
  const float* Wih0 = (const float*)d_in[1];
  const float* Wih  = (const float*)d_in[2];
  const float* Whh  = (const float*)d_in[3];
  const float* bih  = (const float*)d_in[4];
  const float* bhh  = (const float*)d_in[5];
  const float* fcW  = (const float*)d_in[6];
  const float* fcb  = (const float*)d_in[7];
  float* out = (float*)d_out;
  _Float16* seq = (_Float16*)d_ws;

  rnn_fused<<<dim3(BATCH / BB), dim3(512), 0, stream>>>(
      x, Wih0, Wih, Whh, bih, bhh, fcW, fcb, seq, out);
}

// Round 9
// 278.762 us; speedup vs baseline: 1.1311x; 1.1311x over previous
//
#include <hip/hip_runtime.h>
#include <cstdint>
#include <cstddef>

#define HID 128
#define SEQL 28
#define INP 28
#define NL 10
#define NC 10
#define BATCH 4096
#define BB 16             // batch rows per block
#define STRD 136          // padded row stride in halfs (272 B, b128-aligned)
#define BUFH (16 * STRD)  // halfs per 16x128 activation panel

typedef _Float16 half8 __attribute__((ext_vector_type(8)));
typedef _Float16 half4 __attribute__((ext_vector_type(4)));
typedef float    f32x4 __attribute__((ext_vector_type(4)));

// ws: seq [BATCH][SEQL][HID] f16 @ 0 (group-boundary activations; same-block RW only)

__device__ __forceinline__ float tanh_fast(float v) {
  float e = __expf(2.f * v);
  return 1.f - 2.f / (e + 1.f);
}

// 512 threads = 8 waves. Layer groups {0-3},{4-7},{8-9}.
// G0/G1: wave = (l = wid&3, ch = wid>>2) owns layer l, n-cols [64ch,64ch+64), K=256.
// G2   : waves 0-3: (l = wid&1, ch = (wid>>1)&1); wid 4-7 idle.
// ELASTIC systolic: X and O panels TRIPLE-buffered by tick (slot = tau%3,
// compile-time via 3x-unrolled loop). prog[w]=tau+1 posted after wave w ends
// tick tau (lgkmcnt(0) only; global seq traffic drains at group barriers).
// Waits at tick tau: partner >= tau, producers(l-1 pair) >= tau,
// consumers(l+1 pair) >= tau-1  <- the slack that lets producers run ahead
// so flag latency leaves the critical path. Flag check: lanes 0..4 read the
// (up to) 5 neighbor flags in ONE ds_read + __ballot loop.
// Slots: X(s) = s;  O(l,s) = 3 + 3l + s   (15 panels, ~64 KB).
// Cell (l,t=tau-l): INb = l? O(l-1, (tau-1)%3) : X(tau%3);  Hb = O(l,(tau-1)%3);
// writes O(l, tau%3). MFMA: A=weights, B=acts (D col = batch row).
__global__ __launch_bounds__(512, 2) void rnn_fused(
    const float* __restrict__ x,
    const float* __restrict__ Wih0,
    const float* __restrict__ Wih,
    const float* __restrict__ Whh,
    const float* __restrict__ bih,
    const float* __restrict__ bhh,
    const float* __restrict__ fcW,
    const float* __restrict__ fcb,
    _Float16* __restrict__ seq,
    float* __restrict__ out) {
  __shared__ _Float16 lds[BUFH * 15] __attribute__((aligned(16)));
  __shared__ int prog[8];

  const int tid    = threadIdx.x;
  const int lane15 = tid & 15;
  const int quad   = (tid >> 4) & 3;
  const int wid    = tid >> 6;
  const int lane   = tid & 63;
  const int b0     = blockIdx.x * BB;
  const int frow   = lane >> 2;      // fill: 16 rows
  const int fq     = lane & 3;       // fill: 4 col-segments

  half8 bfrag[4][8];
  float biasv[4][4];

  for (int g = 0; g < 3; ++g) {
    const int  NLg    = (g < 2) ? 4 : 2;
    const bool active = (g < 2) || (wid < 4);
    const int  l      = (g < 2) ? (wid & 3) : (wid & 1);
    const int  ch     = (g < 2) ? (wid >> 2) : ((wid >> 1) & 1);
    const int  stride = (g < 2) ? 4 : 2;
    const int  gl     = g * 4 + l;
    const int  tb     = ch * 4;
    const int  TICKS  = SEQL + NLg - 1;
    const bool loader = active && (l == 0) && (g > 0 || ch == 0);
    const bool wr_seq = (g < 2) && (l == NLg - 1);

    // ---- per-lane wait table: lane0=partner, 1/2=producers, 3/4=consumers ----
    int  widx = 0, woff = 0;
    bool wvalid = false;
    if (active) {
      if (lane == 0)                        { widx = (g < 2) ? (wid ^ 4) : (wid ^ 2); woff = 0; wvalid = true; }
      if (lane == 1 && l > 0)               { widx = l - 1;           woff = 0; wvalid = true; }
      if (lane == 2 && l > 0)               { widx = l - 1 + stride;  woff = 0; wvalid = true; }
      if (lane == 3 && l < NLg - 1)         { widx = l + 1;           woff = 1; wvalid = true; }
      if (lane == 4 && l < NLg - 1)         { widx = l + 1 + stride;  woff = 1; wvalid = true; }
    }

    // ---- stage this wave's weights as f16 A-frags (f32 source, L2-hot) ----
    if (active) {
      const float* WihS = (gl == 0) ? Wih0 : Wih + (size_t)(gl - 1) * HID * HID;
      const float* WhhS = Whh + (size_t)gl * HID * HID;
#pragma unroll
      for (int nt = 0; nt < 4; ++nt) {
        const int n = (tb + nt) * 16 + lane15;
#pragma unroll
        for (int ks = 0; ks < 8; ++ks) {
          half8 h;
          if (gl == 0 && ks < 4) {       // layer 0: x zero-padded to 32 cols
            if (ks == 0) {
#pragma unroll
              for (int j = 0; j < 8; ++j) {
                int c = quad * 8 + j;
                h[j] = (_Float16)((c < INP) ? Wih0[n * INP + c] : 0.f);
              }
            } else {
#pragma unroll
              for (int j = 0; j < 8; ++j) h[j] = (_Float16)0.f;  // never used
            }
          } else {
            const float* p = (ks < 4) ? (WihS + (size_t)n * HID + ks * 32 + quad * 8)
                                      : (WhhS + (size_t)n * HID + (ks - 4) * 32 + quad * 8);
            float4 f0 = *(const float4*)p;
            float4 f1 = *(const float4*)(p + 4);
            h[0] = (_Float16)f0.x; h[1] = (_Float16)f0.y;
            h[2] = (_Float16)f0.z; h[3] = (_Float16)f0.w;
            h[4] = (_Float16)f1.x; h[5] = (_Float16)f1.y;
            h[6] = (_Float16)f1.z; h[7] = (_Float16)f1.w;
          }
          bfrag[nt][ks] = h;
        }
#pragma unroll
        for (int r = 0; r < 4; ++r) {
          int nn = (tb + nt) * 16 + quad * 4 + r;
          biasv[nt][r] = bih[gl * HID + nn] + bhh[gl * HID + nn];
        }
      }
    }
    __syncthreads();  // prev group's LDS reads done + its seq stores drained

    {  // zero all 12 O slots (h=0 at t=0)
      uint4 z; z.x = z.y = z.z = z.w = 0u;
      for (int i = tid; i < (BUFH * 12) / 8; i += 512)
        ((uint4*)(lds + 3 * BUFH))[i] = z;
    }
    if (tid < 8) prog[tid] = 0;

    // ---- prefill X(0) with t=0; issue t=1 into regs (2-tick pipeline) ----
    float4 xA0, xA1, xB0, xB1;
    uint4  sA0, sA1, sB0, sB1;
    if (loader) {
      if (g == 0) {
        const float* xb = x + ((size_t)(b0 + frow) * SEQL + 0) * INP + fq * 8;
        xA0 = *(const float4*)xb;
        xA1 = (fq < 3) ? *(const float4*)(xb + 4) : (float4){0.f, 0.f, 0.f, 0.f};
        half8 h;
        h[0] = (_Float16)xA0.x; h[1] = (_Float16)xA0.y;
        h[2] = (_Float16)xA0.z; h[3] = (_Float16)xA0.w;
        h[4] = (_Float16)xA1.x; h[5] = (_Float16)xA1.y;
        h[6] = (_Float16)xA1.z; h[7] = (_Float16)xA1.w;
        *(half8*)(lds + frow * STRD + fq * 8) = h;
        const float* xb1 = x + ((size_t)(b0 + frow) * SEQL + 1) * INP + fq * 8;
        xA0 = *(const float4*)xb1;
        xA1 = (fq < 3) ? *(const float4*)(xb1 + 4) : (float4){0.f, 0.f, 0.f, 0.f};
      } else {
        const int c0 = ch * 64 + fq * 16;
        const _Float16* sp = seq + ((size_t)(b0 + frow) * SEQL + 0) * HID + c0;
        sA0 = *(const uint4*)sp; sA1 = *(const uint4*)(sp + 8);
        *(uint4*)(lds + frow * STRD + c0)     = sA0;
        *(uint4*)(lds + frow * STRD + c0 + 8) = sA1;
        const _Float16* sp1 = seq + ((size_t)(b0 + frow) * SEQL + 1) * HID + c0;
        sA0 = *(const uint4*)sp1; sA1 = *(const uint4*)(sp1 + 8);
      }
    }
    __syncthreads();

    // ---------------- tick body (SC = tau%3 compile-time) ----------------
    auto tick = [&](int tau, int SC) {
      const int SP = (SC + 2) % 3, SN = (SC + 1) % 3;
      const int t  = tau - l;
      // 1. issue global load for input(t = tau+2)
      if (loader && (tau + 2) < SEQL) {
        if (g == 0) {
          const float* xb = x + ((size_t)(b0 + frow) * SEQL + (tau + 2)) * INP + fq * 8;
          xB0 = *(const float4*)xb;
          xB1 = (fq < 3) ? *(const float4*)(xb + 4) : (float4){0.f, 0.f, 0.f, 0.f};
        } else {
          const int c0 = ch * 64 + fq * 16;
          const _Float16* sp = seq + ((size_t)(b0 + frow) * SEQL + (tau + 2)) * HID + c0;
          sB0 = *(const uint4*)sp; sB1 = *(const uint4*)(sp + 8);
        }
      }
      // 2. parallel flag wait: one ds_read + ballot per poll
      {
        const int need = wvalid ? (tau - woff) : (-(1 << 30));
        for (;;) {
          int v = ((volatile int*)prog)[widx];
          if (!__ballot(v < need)) break;
          __builtin_amdgcn_s_sleep(0);
        }
      }
      // 3. compute cell (l, t)
      const bool act = active && (t >= 0) && (t < SEQL);
      if (act) {
        const _Float16* INb = (l == 0) ? lds + SC * BUFH
                                       : lds + (3 + 3 * (l - 1) + SP) * BUFH;
        const _Float16* Hb  = lds + (3 + 3 * l + SP) * BUFH;
        _Float16*       Ob  = lds + (3 + 3 * l + SC) * BUFH;
        half8 af[8];
        if (gl != 0) {
#pragma unroll
          for (int ks = 0; ks < 4; ++ks)
            af[ks] = *(const half8*)(INb + lane15 * STRD + ks * 32 + quad * 8);
        } else {
          af[0] = *(const half8*)(INb + lane15 * STRD + quad * 8);
        }
#pragma unroll
        for (int ks = 0; ks < 4; ++ks)
          af[4 + ks] = *(const half8*)(Hb + lane15 * STRD + ks * 32 + quad * 8);
        f32x4 acc[4];
#pragma unroll
        for (int nt = 0; nt < 4; ++nt)
          acc[nt] = (f32x4){biasv[nt][0], biasv[nt][1], biasv[nt][2], biasv[nt][3]};
        if (gl != 0) {
#pragma unroll
          for (int ks = 0; ks < 4; ++ks)
#pragma unroll
            for (int nt = 0; nt < 4; ++nt)
              acc[nt] = __builtin_amdgcn_mfma_f32_16x16x32_f16(bfrag[nt][ks], af[ks], acc[nt], 0, 0, 0);
        } else {
#pragma unroll
          for (int nt = 0; nt < 4; ++nt)
            acc[nt] = __builtin_amdgcn_mfma_f32_16x16x32_f16(bfrag[nt][0], af[0], acc[nt], 0, 0, 0);
        }
#pragma unroll
        for (int ks = 0; ks < 4; ++ks)
#pragma unroll
          for (int nt = 0; nt < 4; ++nt)
            acc[nt] = __builtin_amdgcn_mfma_f32_16x16x32_f16(bfrag[nt][4 + ks], af[4 + ks], acc[nt], 0, 0, 0);
#pragma unroll
        for (int nt = 0; nt < 4; ++nt) {
          half4 h4;
#pragma unroll
          for (int r = 0; r < 4; ++r) h4[r] = (_Float16)tanh_fast(acc[nt][r]);
          const int n4 = (tb + nt) * 16 + quad * 4;
          *(half4*)(Ob + lane15 * STRD + n4) = h4;
          if (wr_seq)   // consumed next group (after a real __syncthreads)
            *(half4*)(seq + ((size_t)(b0 + lane15) * SEQL + t) * HID + n4) = h4;
        }
      }
      // 4. store input(t = tau+1) into X(SN) -- before flag post
      if (loader && (tau + 1) < SEQL) {
        if (g == 0) {
          half8 h;
          h[0] = (_Float16)xA0.x; h[1] = (_Float16)xA0.y;
          h[2] = (_Float16)xA0.z; h[3] = (_Float16)xA0.w;
          h[4] = (_Float16)xA1.x; h[5] = (_Float16)xA1.y;
          h[6] = (_Float16)xA1.z; h[7] = (_Float16)xA1.w;
          *(half8*)(lds + SN * BUFH + frow * STRD + fq * 8) = h;
          xA0 = xB0; xA1 = xB1;
        } else {
          const int c0 = ch * 64 + fq * 16;
          *(uint4*)(lds + SN * BUFH + frow * STRD + c0)     = sA0;
          *(uint4*)(lds + SN * BUFH + frow * STRD + c0 + 8) = sA1;
          sA0 = sB0; sA1 = sB1;
        }
      }
      // 5. post progress: LDS writes drained; global queue stays in flight
      __asm__ __volatile__("s_waitcnt lgkmcnt(0)" ::: "memory");
      if (lane == 0) *(volatile int*)(prog + wid) = tau + 1;
    };

    for (int tau0 = 0; tau0 < TICKS; tau0 += 3) {  // slot = tau%3 compile-time
      tick(tau0, 0);
      if (tau0 + 1 < TICKS) tick(tau0 + 1, 1);
      if (tau0 + 2 < TICKS) tick(tau0 + 2, 2);
    }
  }
  __syncthreads();

  // --- FC on layer-9 h at t=27: G2 local l=1, tau=28, slot 28%3=1 -> O(1,1)=panel 7 ---
  if (tid < BB * NC) {
    int c = tid >> 4;
    int b = tid & 15;
    float a = fcb[c];
    const float* wr = fcW + c * HID;
    const _Float16* hr = lds + 7 * BUFH + b * STRD;
#pragma unroll 4
    for (int k = 0; k < HID; ++k) a += (float)hr[k] * wr[k];
    out[(size_t)(b0 + b) * NC + c] = a;
  }
}

extern "C" void kernel_launch(void* const* d_in, const int* in_sizes, int n_in,
                              void* d_out, int out_size, void* d_ws, size_t ws_size,
                              hipStream_t stream) {
  const float* x    = (const float*)d_in[0];
  const float* Wih0 = (const float*)d_in[1];
  const float* Wih  = (const float*)d_in[2];
  const float* Whh  = (const float*)d_in[3];
  const float* bih  = (const float*)d_in[4];
  const float* bhh  = (const float*)d_in[5];
  const float* fcW  = (const float*)d_in[6];
  const float* fcb  = (const float*)d_in[7];
  float* out = (float*)d_out;
  _Float16* seq = (_Float16*)d_ws;

  rnn_fused<<<dim3(BATCH / BB), dim3(512), 0, stream>>>(
      x, Wih0, Wih, Whh, bih, bhh, fcW, fcb, seq, out);
}